// Round 6
// baseline (2962.737 us; speedup 1.0000x reference)
//
#include <hip/hip_runtime.h>
#include <hip/hip_bf16.h>

#define DEV __device__ __forceinline__

typedef __bf16 bf16x8 __attribute__((ext_vector_type(8)));
typedef float  f32x4  __attribute__((ext_vector_type(4)));
typedef unsigned short u16;
typedef unsigned long long u64;

DEV u16   f2b(float f) { __bf16 h = (__bf16)f; return __builtin_bit_cast(u16, h); }
DEV float b2f(u16 x)   { return __builtin_bit_cast(float, ((unsigned)x) << 16); }

// system-scope (L3-coherent) per-access ops — no cache-wide fences anywhere
DEV float ldf(const float* p)   { return __hip_atomic_load(p, __ATOMIC_RELAXED, __HIP_MEMORY_SCOPE_SYSTEM); }
DEV u64   ld64(const void* p)   { return __hip_atomic_load((const u64*)p, __ATOMIC_RELAXED, __HIP_MEMORY_SCOPE_SYSTEM); }
DEV void  stf(float* p, float v){ __hip_atomic_store(p, v, __ATOMIC_RELAXED, __HIP_MEMORY_SCOPE_SYSTEM); }
DEV void  st32(unsigned* p, unsigned v) { __hip_atomic_store(p, v, __ATOMIC_RELAXED, __HIP_MEMORY_SCOPE_SYSTEM); }
DEV void  st64(void* p, u64 v)  { __hip_atomic_store((u64*)p, v, __ATOMIC_RELAXED, __HIP_MEMORY_SCOPE_SYSTEM); }

DEV void gl_lds16(const u16* g, u16* l) {
  __builtin_amdgcn_global_load_lds((const __attribute__((address_space(1))) void*)g,
                                   (__attribute__((address_space(3))) void*)l, 16, 0, 0);
}

#define WAITV(n) asm volatile("s_waitcnt vmcnt(" #n ")" ::: "memory")
#define WAITL    asm volatile("s_waitcnt lgkmcnt(0)" ::: "memory")
#define SBAR0    __builtin_amdgcn_sched_barrier(0)

// fence-free grid barrier (monotonic, zeroed by k_init each launch)
DEV void gridbar(unsigned* bar, unsigned& gen) {
  __syncthreads();
  if (threadIdx.x == 0) {
    gen += 256u;   // NWG
    __hip_atomic_fetch_add(bar, 1u, __ATOMIC_RELAXED, __HIP_MEMORY_SCOPE_SYSTEM);
    while (__hip_atomic_load(bar, __ATOMIC_RELAXED, __HIP_MEMORY_SCOPE_SYSTEM) < gen)
      __builtin_amdgcn_s_sleep(2);
  }
  __syncthreads();
}

// ---------------------------------------------------------------------------
// Pipelined 64x32-tile GEMM core over a virtual K=2048 made of two halves
// (kt<1024 -> source0, else source1). D[m,e] = sum A[m,k]*B[e,k].
// A: bypass ld64 reg-prefetch 2 tiles deep -> swizzled ds_write.
// B: global_load_lds (cached), 1 tile deep. Counted vmcnt, raw s_barrier.
// MODE 0=P1 (chain out, +pre, opt lC)  1=P3A (hall/out0 only)
//      2=P3B (hall/out0 + chain)       3=SQ (outb + outbT, bypass u32)
//      4=PRE (+bias, plain stores)
// ---------------------------------------------------------------------------
template<int MODE>
DEV void gemm_core(u16* sm,
                   const u16* a0p, int a0pre, int a0ct,
                   const u16* a1p, int a1pre, int a1ct,
                   const u16* b0, const u16* b1, int kstart,
                   int m0, int e0, const u16* preb, const float* bias,
                   u16* outb, u16* outbT, float* lC,
                   float* hall, float* out0, int ctadd, int tq)
{
  int tid = threadIdx.x, lane = tid & 63, w = tid >> 6;
  int wrow = (w >> 1) << 5, wcol = (w & 1) << 4;
  u16* As = sm;            // [2][8192] u16 (16KB per buf)
  u16* Bs = sm + 16384;    // [2][4096] u16 (8KB per buf)
  f32x4 acc[2] = {};

  int rB[2], cB[2];
#pragma unroll
  for (int j = 0; j < 2; ++j) {
    int p = (j * 4 + w) * 1024 + lane * 16;
    int r = p >> 8, o = (p & 255) ^ ((r & 7) << 4);
    rB[j] = r; cB[j] = o >> 1;
  }
  auto stageB = [&](int bufb, int kt) {
    const u16* bp = (kt >> 10) ? b1 : b0;
    int kl = kt & 1023;
#pragma unroll
    for (int j = 0; j < 2; ++j)
      gl_lds16(bp + (size_t)(e0 + rB[j]) * 1024 + kl + cB[j], Bs + bufb * 4096 + (j * 4 + w) * 512);
  };

  int arl = tid >> 2;           // local A row 0..63
  int ac0 = (tid & 3) * 4;      // 16B-slot base within 256B row
  auto aload = [&](int kt, u64* va) {
    int half = kt >> 10;
    const u16* ap = half ? a1p : a0p;
    int ispre = half ? a1pre : a0pre;
    int ct    = half ? a1ct  : a0ct;
    int row = m0 + arl;
    long r = ispre ? ((long)((row >> 3) * 32 + ct) * 8 + (row & 7)) : (long)row;
    const u16* base = ap + r * 1024 + (kt & 1023);
#pragma unroll
    for (int j = 0; j < 4; ++j) {
      const u64* p = (const u64*)(base + (ac0 + j) * 8);
      va[2 * j]     = ld64(p);
      va[2 * j + 1] = ld64(p + 1);
    }
  };
  auto awrite = [&](int bufb, const u64* va) {
#pragma unroll
    for (int j = 0; j < 4; ++j) {
      int c16 = ac0 + j;
      int off = arl * 256 + ((c16 * 16) ^ ((arl & 7) << 4));
      uint4 v;
      v.x = (unsigned)va[2 * j];     v.y = (unsigned)(va[2 * j] >> 32);
      v.z = (unsigned)va[2 * j + 1]; v.w = (unsigned)(va[2 * j + 1] >> 32);
      *(uint4*)((char*)(As + bufb * 8192) + off) = v;
    }
  };
  auto compute = [&](int bufb) {
#pragma unroll
    for (int ks = 0; ks < 4; ++ks) {
      int oa = ks * 64 + ((lane >> 4) << 4);
      int ra0 = wrow + (lane & 15), ra1 = ra0 + 16, rb = wcol + (lane & 15);
      bf16x8 af0 = *(const bf16x8*)((const char*)(As + bufb * 8192) + ra0 * 256 + (oa ^ ((ra0 & 7) << 4)));
      bf16x8 af1 = *(const bf16x8*)((const char*)(As + bufb * 8192) + ra1 * 256 + (oa ^ ((ra1 & 7) << 4)));
      bf16x8 bv  = *(const bf16x8*)((const char*)(Bs + bufb * 4096) + rb * 256 + (oa ^ ((rb & 7) << 4)));
      acc[0] = __builtin_amdgcn_mfma_f32_16x16x32_bf16(af0, bv, acc[0], 0, 0, 0);
      acc[1] = __builtin_amdgcn_mfma_f32_16x16x32_bf16(af1, bv, acc[1], 0, 0, 0);
    }
  };

  u64 vA[8], vB[8];
  const int LASTK = 2048 - 128;
  // prologue: B(k0)+A(k0)+A(k0+128); wait B0+A0 (leave A1 in flight)
  stageB(0, kstart);  SBAR0;
  aload(kstart, vA);  SBAR0;
  { int c1 = kstart + 128 > LASTK ? LASTK : kstart + 128; aload(c1, vB); }
  WAITV(8); SBAR0;
  awrite(0, vA);
  WAITL; SBAR0;
  __builtin_amdgcn_s_barrier();

  int NI = (2048 - kstart) >> 7;   // 8 or 16 (even)
  int cur = 0;
#pragma unroll 2
  for (int it = 0; it < NI; ++it) {
    int kt  = kstart + (it << 7);
    int ktB = kt + 128 > LASTK ? LASTK : kt + 128;
    int ktA = kt + 256 > LASTK ? LASTK : kt + 256;
    stageB(cur ^ 1, ktB);  SBAR0;                  // +2 (next B)
    u64* vaNext = (it & 1) ? vA : vB;              // holds A(kt+128)
    u64* vaFar  = (it & 1) ? vB : vA;
    aload(ktA, vaFar);  SBAR0;                     // +8 (A two ahead)
    compute(cur);
    WAITV(10); SBAR0;                              // A(kt+128) arrived
    awrite(cur ^ 1, vaNext);
    WAITV(8); WAITL; SBAR0;                        // next-B in LDS, ds_writes done
    __builtin_amdgcn_s_barrier();
    cur ^= 1;
  }
  WAITV(0);                                        // drain clamped prefetches

  int l4 = ((lane >> 4) << 2), lc = lane & 15;
#pragma unroll
  for (int s = 0; s < 2; ++s)
#pragma unroll
    for (int j = 0; j < 4; ++j) {
      int row = m0 + wrow + s * 16 + l4 + j;   // C/D: row=(lane>>4)*4+reg
      int col = e0 + wcol + lc;                // C/D: col=lane&15
      float v = acc[s][j];
      if (MODE == 4) {
        v += bias[col];
        outb[(size_t)row * 1024 + col] = f2b(v);
      } else if (MODE == 3) {
        u16 h = f2b(v);
        unsigned other = (unsigned)(u16)__shfl_xor((int)h, 1);
        if (!(lane & 1)) st32((unsigned*)(outb + row * 1024 + col), (unsigned)h | (other << 16));
      } else {
        int chunk = row >> 3, b = row & 7;
        v += b2f(preb[((size_t)(chunk * 32 + ctadd) * 8 + b) * 1024 + col]);
        if (MODE == 0) {
          u16 h = f2b(v);
          unsigned other = (unsigned)(u16)__shfl_xor((int)h, 1);
          if (!(lane & 1)) st32((unsigned*)(outb + row * 1024 + col), (unsigned)h | (other << 16));
          if (lC) stf(lC + row * 1024 + col, v);
        } else {
          int t = chunk * 32 + tq;
          hall[(size_t)t * 8192 + b * 1024 + col] = v;            // h_all[t]
          float sg = 1.f / (1.f + __expf(-v));
          out0[(size_t)(t - 1) * 8192 + b * 1024 + col] = v * v * sg;
          if (MODE == 2) {
            u16 h = f2b(v);
            unsigned other = (unsigned)(u16)__shfl_xor((int)h, 1);
            if (!(lane & 1)) st32((unsigned*)(outb + row * 1024 + col), (unsigned)h | (other << 16));
          }
        }
      }
    }
  if (MODE == 3 && outbT) {
#pragma unroll
    for (int s = 0; s < 2; ++s)
#pragma unroll
      for (int j = 0; j < 4; j += 2) {
        int row = m0 + wrow + s * 16 + l4 + j;
        int col = e0 + wcol + lc;
        unsigned wv = (unsigned)f2b(acc[s][j]) | ((unsigned)f2b(acc[s][j + 1]) << 16);
        st32((unsigned*)(outbT + (size_t)col * 1024 + row), wv);
      }
  }
}

// matvec: hout[r,e] = sum_d W[e,d]*hin[r,d] + addv[map(r),e]; fp32 bypass state
DEV void matvec_unit(int tid, int e16, int rblk, const float* hin,
                     const u16* W, const float* addv,
                     float* hout, u16* houtb, int acoff, int bcoff, bool nr64)
{
  int lg = tid & 15, eg = tid >> 4;
  int e = e16 * 16 + eg;
  int r0 = rblk * 8;
  float acc[8] = {0,0,0,0,0,0,0,0};
  const u16* wrow = W + e * 1024;
#pragma unroll
  for (int i = 0; i < 8; ++i) {
    int d0 = lg * 8 + i * 128;
    ushort4 w0 = *(const ushort4*)(wrow + d0);
    ushort4 w1 = *(const ushort4*)(wrow + d0 + 4);
    float wa = b2f(w0.x), wb = b2f(w0.y), wc = b2f(w0.z), wd = b2f(w0.w);
    float we_ = b2f(w1.x), wf = b2f(w1.y), wg = b2f(w1.z), wh = b2f(w1.w);
#pragma unroll
    for (int b = 0; b < 8; ++b) {
      const float* hr = hin + (r0 + b) * 1024 + d0;
      u64 q0 = ld64(hr), q1 = ld64(hr + 2), q2 = ld64(hr + 4), q3 = ld64(hr + 6);
      float2 f0 = __builtin_bit_cast(float2, q0), f1 = __builtin_bit_cast(float2, q1);
      float2 f2 = __builtin_bit_cast(float2, q2), f3 = __builtin_bit_cast(float2, q3);
      acc[b] += wa*f0.x + wb*f0.y + wc*f1.x + wd*f1.y
              + we_*f2.x + wf*f2.y + wg*f3.x + wh*f3.y;
    }
  }
#pragma unroll
  for (int m = 1; m < 16; m <<= 1)
#pragma unroll
    for (int b = 0; b < 8; ++b) acc[b] += __shfl_xor(acc[b], m);
  if (lg == 0) {
#pragma unroll
    for (int b = 0; b < 8; ++b) {
      int r = r0 + b;
      int ai = nr64 ? (((r >> 3) << 6) + (acoff << 3) + (r & 7)) : r;
      float v = acc[b] + ldf(addv + ai * 1024 + e);
      stf(hout + r * 1024 + e, v);
      if (houtb) {
        int bi = nr64 ? (((r >> 3) << 6) + (bcoff << 3) + (r & 7)) : r;
        u16 h = f2b(v);
        unsigned other = (unsigned)(u16)__shfl_xor((int)h, 16);
        if (!(eg & 1)) st32((unsigned*)(houtb + bi * 1024 + e), (unsigned)h | (other << 16));
      }
    }
  }
}

// standalone pre-GEMM: pre = x_bf16 @ Wx^T + b  (8192 WGs, full occupancy)
__global__ __launch_bounds__(256) void pre_kernel(const u16* __restrict__ xb,
                                                  const u16* __restrict__ wxb,
                                                  const float* __restrict__ bias,
                                                  u16* __restrict__ pre_b)
{
  __shared__ u16 sm[24576];
  int e0 = blockIdx.x * 32, m0 = blockIdx.y * 64;
  gemm_core<4>(sm, xb, 0, 0, xb, 0, 0, wxb, wxb, 1024, m0, e0,
               nullptr, bias, pre_b, nullptr, nullptr, nullptr, nullptr, 0, 0);
}

// ---------------------------------------------------------------------------
// Persistent kernel: squarings, phase1 (16 double-steps), phase2, phase3
// (16 double-steps). 256 WGs x 256 threads, ~62 fence-free grid barriers.
// ---------------------------------------------------------------------------
__global__ __launch_bounds__(256) void persist(char* __restrict__ ws, float* out0)
{
  u16*   pre_b = (u16*)(ws);
  u16*   wh_b  = (u16*)(ws + 33554432);
  u16*   whT_b = (u16*)(ws + 35651584);
  u16*   W2    = (u16*)(ws + 37748736);   // Wh^2  (read through phase3!)
  u16*   W2T   = (u16*)(ws + 39845888);
  float* lC    = (float*)(ws + 46137344);
  u16*   lb0   = (u16*)(ws + 48234496);
  u16*   lb1   = (u16*)(ws + 49283072);
  u16*   bnd_b = (u16*)(ws + 50331648);
  float* lam0  = (float*)(ws + 51380224);
  float* lam1  = (float*)(ws + 51642368);
  float* bndS  = (float*)(ws + 51904512);
  float* pc0   = (float*)(ws + 52166656);
  float* pc1   = (float*)(ws + 52428800);
  unsigned* bar = (unsigned*)(ws + 52711424);

  float* hall = out0 + 16777216;
  // transient power buffers in hall region (dead until phase3; W32/W256 read
  // only in phase2, which precedes all phase3 hall writes)
  char* hb = (char*)hall;
  u16* pw[15];
#pragma unroll
  for (int i = 0; i < 15; ++i) pw[i] = (u16*)(hb + 20971520 + (size_t)i * 2097152);
  u16* W32  = pw[8];
  u16* W256 = pw[14];

  __shared__ u16 sm[24576];   // 48KB
  int g = blockIdx.x, tid = threadIdx.x;
  unsigned gen = 0;

  // ---- Wh powers by squaring: 8 steps, 512 tiles each (2/WG) ----
  const u16* qa[8]  = {wh_b,  W2,  pw[2], pw[4], pw[6], pw[8],  pw[10], pw[12]};
  const u16* qat[8] = {whT_b, W2T, pw[3], pw[5], pw[7], pw[9],  pw[11], pw[13]};
  u16*       qo[8]  = {W2,    pw[2], pw[4], pw[6], pw[8], pw[10], pw[12], pw[14]};
  u16*       qot[8] = {W2T,   pw[3], pw[5], pw[7], pw[9], pw[11], pw[13], nullptr};
  for (int sq = 0; sq < 8; ++sq) {
    for (int i = 0; i < 2; ++i) {
      int t = i * 256 + g;
      gemm_core<3>(sm, qa[sq], 0, 0, qa[sq], 0, 0, qat[sq], qat[sq], 1024,
                   (t >> 5) * 64, (t & 31) * 32, nullptr, nullptr,
                   qo[sq], qot[sq], nullptr, nullptr, nullptr, 0, 0);
    }
    gridbar(bar, gen);
  }

  int mt = g & 7, et = g >> 3;
  int m0 = mt * 64, e0 = et * 32;

  // ---- phase 1: 16 double-steps: l_{2k} = [l_{2k-2}|pre(2k-2)]*[W2;Wh]^T + pre(2k-1)
  for (int k = 1; k <= 16; ++k) {
    const u16* chain = (k == 1) ? lb0 : ((k & 1) ? lb0 : lb1);  // prev out lb[(k-1)&1]
    u16* out = (k & 1) ? lb1 : lb0;
    gemm_core<0>(sm, chain, 0, 0, pre_b, 1, 2 * k - 2, W2, wh_b,
                 (k == 1) ? 1024 : 0, m0, e0, pre_b, nullptr,
                 out, nullptr, (k == 16) ? lC : nullptr, nullptr, nullptr,
                 2 * k - 1, 0);
    gridbar(bar, gen);
  }

  // ---- gather: lam0[s*8+b] = lC row of chunk s*8 ----
  {
    int ii = g * 256 + tid;
    if (ii < 16384) {
      int r = ii >> 8, e4 = (ii & 255) * 4;
      int src = ((r >> 3) << 6) + (r & 7);
      const u64* sp = (const u64*)(lC + src * 1024 + e4);
      st64(lam0 + r * 1024 + e4, sp[0]);
      st64(lam0 + r * 1024 + e4 + 2, sp[1]);
    }
  }
  gridbar(bar, gen);

  // ---- phase 2a: Lambda chain (7 steps, W32) ----
  for (int c = 2; c <= 8; ++c) {
    const float* in = (c & 1) ? lam1 : lam0;
    float* out = (c & 1) ? lam0 : lam1;
    for (int i = 0; i < 2; ++i) {
      int u = i * 256 + g;
      matvec_unit(tid, u & 63, u >> 6, in, W32, lC, out, nullptr, c - 1, 0, true);
    }
    gridbar(bar, gen);
  }
  // ---- phase 2b: superchunk chain (7 steps, W256) ----
  for (int s = 0; s < 7; ++s) {
    if (g < 64)
      matvec_unit(tid, g, 0, bndS + s * 8192, W256, lam1 + s * 8192,
                  bndS + (s + 1) * 8192, bnd_b + (size_t)(s + 1) * 65536, 0, 0, false);
    gridbar(bar, gen);
  }
  // ---- phase 2c: intra-super boundaries (7 steps, W32) ----
  for (int c = 1; c <= 7; ++c) {
    const float* in = (c == 1) ? bndS : ((c & 1) ? pc1 : pc0);
    float* out = (c & 1) ? pc0 : pc1;
    for (int i = 0; i < 2; ++i) {
      int u = i * 256 + g;
      matvec_unit(tid, u & 63, u >> 6, in, W32, lC, out, bnd_b, c - 1, c, true);
    }
    gridbar(bar, gen);
  }

  // ---- phase 3: 16 double-steps; each = tileA (h_{2k-1}) + tileB (h_{2k}) ----
  for (int k = 1; k <= 16; ++k) {
    const u16* chain = (k == 1) ? bnd_b : ((k & 1) ? lb0 : lb1);
    u16* out = (k & 1) ? lb1 : lb0;
    // h_{2k-1} = Wh*h_{2k-2} + pre(ct=2k-2); outputs hall/out0 only
    gemm_core<1>(sm, chain, 0, 0, chain, 0, 0, wh_b, wh_b, 1024,
                 m0, e0, pre_b, nullptr, nullptr, nullptr, nullptr,
                 hall, out0, 2 * k - 2, 2 * k - 1);
    // h_{2k} = W2*h_{2k-2} + Wh*pre(2k-2) + pre(2k-1); chain out + hall/out0
    gemm_core<2>(sm, chain, 0, 0, pre_b, 1, 2 * k - 2, W2, wh_b, 0,
                 m0, e0, pre_b, nullptr, out, nullptr, nullptr,
                 hall, out0, 2 * k - 1, 2 * k);
    if (k < 16) gridbar(bar, gen);
  }
}

// ---- power iteration + misc helpers -----------------------------------------
__global__ void k_init(const float* __restrict__ u_in, const float* __restrict__ h0,
                       float* __restrict__ u_cur, float* __restrict__ v_acc,
                       float* __restrict__ u_acc, float* __restrict__ hall0,
                       float* __restrict__ bndS, u16* __restrict__ bndb,
                       unsigned* __restrict__ bar)
{
  int i = blockIdx.x * 256 + threadIdx.x;
  if (i == 0) *bar = 0u;
  if (i < 1024) { u_cur[i] = u_in[i]; v_acc[i] = 0.f; u_acc[i] = 0.f; }
  if (i < 8192) { float h = h0[i]; hall0[i] = h; bndS[i] = h; bndb[i] = f2b(h); }
}

__global__ void k_v(const float* __restrict__ W, const float* __restrict__ u_cur,
                    float* __restrict__ v_acc)
{
  int d = blockIdx.x * 256 + threadIdx.x;
  int e0 = blockIdx.y * 64;
  float a = 0.f;
  for (int e = e0; e < e0 + 64; ++e) a += W[e * 1024 + d] * u_cur[e];
  atomicAdd(&v_acc[d], a);
}

__global__ void k_u(const float* __restrict__ W, const float* __restrict__ v_cur,
                    float* __restrict__ u_acc)
{
  int lg = threadIdx.x & 15, ei = threadIdx.x >> 4;
  int e = blockIdx.y * 16 + ei;
  int d0 = blockIdx.x * 512;
  float a = 0.f;
  for (int i = 0; i < 32; ++i) { int d = d0 + lg + 16 * i; a += W[e * 1024 + d] * v_cur[d]; }
#pragma unroll
  for (int m = 1; m < 16; m <<= 1) a += __shfl_xor(a, m);
  if (lg == 0) atomicAdd(&u_acc[e], a);
}

__global__ void k_norm(const float* __restrict__ acc, float* __restrict__ outv,
                       float* __restrict__ z1)
{
  __shared__ float red[16];
  int t = threadIdx.x;
  float x = acc[t];
  float ss = x * x;
#pragma unroll
  for (int m = 1; m < 64; m <<= 1) ss += __shfl_xor(ss, m);
  if ((t & 63) == 0) red[t >> 6] = ss;
  __syncthreads();
  if (t < 64) {
    float s = (t < 16) ? red[t] : 0.f;
#pragma unroll
    for (int m = 1; m < 16; m <<= 1) s += __shfl_xor(s, m);
    if (t == 0) red[0] = s;
  }
  __syncthreads();
  float nrm = sqrtf(red[0]) + 1e-8f;
  outv[t] = x / nrm;
  z1[t] = 0.f;
}

__global__ void k_sigma(const float* __restrict__ acc, float* __restrict__ scale)
{
  __shared__ float red[16];
  int t = threadIdx.x;
  float x = acc[t];
  float ss = x * x;
#pragma unroll
  for (int m = 1; m < 64; m <<= 1) ss += __shfl_xor(ss, m);
  if ((t & 63) == 0) red[t >> 6] = ss;
  __syncthreads();
  if (t < 64) {
    float s = (t < 16) ? red[t] : 0.f;
#pragma unroll
    for (int m = 1; m < 16; m <<= 1) s += __shfl_xor(s, m);
    if (t == 0) {
      float sigma = s / (sqrtf(s) + 1e-8f);
      scale[0] = 0.95f / (sigma + 1e-8f);
    }
  }
}

__global__ void k_scale(const float* __restrict__ W, const float* __restrict__ scale,
                        u16* __restrict__ wb, u16* __restrict__ wbT)
{
  int i = blockIdx.x * 256 + threadIdx.x;
  float v = W[i] * scale[0];
  u16 h = f2b(v);
  wb[i] = h;
  wbT[(i & 1023) * 1024 + (i >> 10)] = h;
}

__global__ void k_cvt(const float* __restrict__ in, u16* __restrict__ out, int n)
{
  int i = (blockIdx.x * 256 + threadIdx.x) * 4;
  if (i >= n) return;
  float4 v = *(const float4*)(in + i);
  ushort4 o;
  o.x = f2b(v.x); o.y = f2b(v.y); o.z = f2b(v.z); o.w = f2b(v.w);
  *(ushort4*)(out + i) = o;
}

extern "C" void kernel_launch(void* const* d_in, const int* in_sizes, int n_in,
                              void* d_out, int out_size, void* d_ws, size_t ws_size,
                              hipStream_t stream)
{
  (void)in_sizes; (void)n_in; (void)out_size; (void)ws_size;
  const float* x  = (const float*)d_in[0];
  const float* h0 = (const float*)d_in[1];
  const float* Wx = (const float*)d_in[2];
  const float* Wh = (const float*)d_in[3];
  const float* bv = (const float*)d_in[4];
  const float* uv = (const float*)d_in[5];

  float* out0 = (float*)d_out;
  float* hall = out0 + 16777216;

  char* ws = (char*)d_ws;
  u16*   pre_b = (u16*)(ws);
  u16*   wh_b  = (u16*)(ws + 33554432);
  u16*   whT_b = (u16*)(ws + 35651584);
  u16*   wxb   = (u16*)(ws + 48234496);   // spans lb0+lb1, dead before phase1
  u16*   bnd_b = (u16*)(ws + 50331648);
  float* bndS  = (float*)(ws + 51904512);
  float* u_cur = (float*)(ws + 52690944);
  float* v_cur = u_cur + 1024;
  float* v_acc = u_cur + 2048;
  float* u_acc = u_cur + 3072;
  float* scale = u_cur + 4096;
  unsigned* bar = (unsigned*)(ws + 52711424);
  u16*   xb    = (u16*)d_out;             // x bf16 staged in out0 (dead before phase3)

  k_init<<<32, 256, 0, stream>>>(uv, h0, u_cur, v_acc, u_acc, hall, bndS, bnd_b, bar);

  for (int it = 0; it < 3; ++it) {
    k_v<<<dim3(4, 16), 256, 0, stream>>>(Wh, u_cur, v_acc);
    k_norm<<<1, 1024, 0, stream>>>(v_acc, v_cur, u_acc);
    k_u<<<dim3(2, 64), 256, 0, stream>>>(Wh, v_cur, u_acc);
    if (it < 2) k_norm<<<1, 1024, 0, stream>>>(u_acc, u_cur, v_acc);
    else        k_sigma<<<1, 1024, 0, stream>>>(u_acc, scale);
  }
  k_scale<<<4096, 256, 0, stream>>>(Wh, scale, wh_b, whT_b);

  k_cvt<<<16384, 256, 0, stream>>>(x, xb, 16777216);
  k_cvt<<<1024, 256, 0, stream>>>(Wx, wxb, 1048576);

  // pre-GEMM as a normal full-occupancy launch (latency hidden by TLP)
  pre_kernel<<<dim3(32, 256), 256, 0, stream>>>(xb, wxb, bv, pre_b);

  void* kargs[2];
  char* ws_a = ws; float* o0_a = out0;
  kargs[0] = &ws_a; kargs[1] = &o0_a;
  hipLaunchCooperativeKernel((void*)persist, dim3(256), dim3(256), kargs, 0, stream);
}

// Round 7
// 946.364 us; speedup vs baseline: 3.1307x; 3.1307x over previous
//
#include <hip/hip_runtime.h>
#include <hip/hip_bf16.h>

#define DEV __device__ __forceinline__

typedef __bf16 bf16x8 __attribute__((ext_vector_type(8)));
typedef float  f32x4  __attribute__((ext_vector_type(4)));
typedef unsigned short u16;

DEV u16   f2b(float f) { __bf16 h = (__bf16)f; return __builtin_bit_cast(u16, h); }
DEV float b2f(u16 x)   { return __builtin_bit_cast(float, ((unsigned)x) << 16); }

DEV void gl_lds16(const u16* g, u16* l) {
  __builtin_amdgcn_global_load_lds((const __attribute__((address_space(1))) void*)g,
                                   (__attribute__((address_space(3))) void*)l, 16, 0, 0);
}

// ---------------------------------------------------------------------------
// Generic 64x64-tile GEMM over virtual K = nseg*1024 (segments of the A
// operand; B is one row-major matrix with stride bstr, columns boff..boff+K).
// BK=128 double-buffered LDS, issue-early staging (R4-proven structure).
// A segment row map: plain (grow) or pre-time map ((grow>>3)*32+ct)*8+(grow&7).
// MODE 0: PRE  (v+=bias, write pre_b)
// MODE 1: SQ   (write o1 [+o1T] [+Bcat slot o2@o2coff])
// MODE 2: P1   (v+=pre[addct], write chain bf16 [+lC fp32])
// MODE 3: P3   (q=z+1: K=q*1024, boff=(4-q)*1024; v+=pre; write hall/out0,
//               q==4 also chain bf16)
// ---------------------------------------------------------------------------
template<int MODE>
__global__ __launch_bounds__(256) void gK(
    const u16* __restrict__ chain, const u16* __restrict__ preb,
    int ctoff, unsigned aflags, int nseg_a, int boff_a,
    const u16* __restrict__ B, int bstr,
    const float* __restrict__ bias, int addct_a,
    u16* __restrict__ o1, u16* __restrict__ o1T,
    u16* __restrict__ o2, int o2coff,
    float* __restrict__ fout, float* __restrict__ out0, int tbase)
{
  int q = 0, nseg, boff, addct;
  if (MODE == 3) { q = blockIdx.z + 1; nseg = q; boff = (4 - q) << 10; addct = tbase + q - 1; }
  else           { nseg = nseg_a; boff = boff_a; addct = addct_a; }
  const int K = nseg << 10;

  int tid = threadIdx.x, lane = tid & 63, w = tid >> 6;
  int wrow = (w >> 1) << 5, wcol = (w & 1) << 5;
  int m0 = blockIdx.y << 6, e0 = blockIdx.x << 6;

  __shared__ u16 As[2][8192], Bs[2][8192];   // 2 x 16KB each = 64KB
  f32x4 acc[2][2] = {};

  int rA[4], cA[4];
#pragma unroll
  for (int j = 0; j < 4; ++j) {
    int p = (j * 4 + w) * 1024 + lane * 16;
    int r = p >> 8, o = (p & 255) ^ ((r & 7) << 4);
    rA[j] = r; cA[j] = o >> 1;
  }
  auto stage = [&](int buf, int kt) {
    int seg = kt >> 10, kl = kt & 1023;
    bool isp = (aflags >> seg) & 1;
    const u16* ap = isp ? preb : chain;
    int ct = ctoff + seg;
#pragma unroll
    for (int j = 0; j < 4; ++j) {
      int grow = m0 + rA[j];
      long ar = isp ? ((long)((grow >> 3) * 32 + ct) * 8 + (grow & 7)) : (long)grow;
      gl_lds16(ap + ar * 1024 + kl + cA[j], &As[buf][(j * 4 + w) * 512]);
    }
#pragma unroll
    for (int j = 0; j < 4; ++j)
      gl_lds16(B + (size_t)(e0 + rA[j]) * bstr + boff + kt + cA[j], &Bs[buf][(j * 4 + w) * 512]);
  };

  stage(0, 0);
  asm volatile("s_waitcnt vmcnt(0)" ::: "memory");
  __syncthreads();

  int buf = 0;
  for (int kt = 0; kt < K; kt += 128, buf ^= 1) {
    if (kt + 128 < K) stage(buf ^ 1, kt + 128);
#pragma unroll
    for (int ks = 0; ks < 4; ++ks) {
      int oa = ks * 64 + ((lane >> 4) << 4);
      bf16x8 af[2], bf[2];
#pragma unroll
      for (int s = 0; s < 2; ++s) {
        int ra = wrow + s * 16 + (lane & 15);
        int rb = wcol + s * 16 + (lane & 15);
        af[s] = *(const bf16x8*)((const char*)&As[buf][0] + ra * 256 + (oa ^ ((ra & 7) << 4)));
        bf[s] = *(const bf16x8*)((const char*)&Bs[buf][0] + rb * 256 + (oa ^ ((rb & 7) << 4)));
      }
#pragma unroll
      for (int ms = 0; ms < 2; ++ms)
#pragma unroll
        for (int ns = 0; ns < 2; ++ns)
          acc[ms][ns] = __builtin_amdgcn_mfma_f32_16x16x32_bf16(af[ms], bf[ns], acc[ms][ns], 0, 0, 0);
    }
    asm volatile("s_waitcnt vmcnt(0)" ::: "memory");
    __syncthreads();
  }

  int l4 = ((lane >> 4) << 2), lc = lane & 15;
#pragma unroll
  for (int ms = 0; ms < 2; ++ms)
#pragma unroll
    for (int ns = 0; ns < 2; ++ns)
#pragma unroll
      for (int j = 0; j < 4; ++j) {
        int row = m0 + wrow + ms * 16 + l4 + j;   // C/D: row=(lane>>4)*4+reg
        int col = e0 + wcol + ns * 16 + lc;       // C/D: col=lane&15
        float v = acc[ms][ns][j];
        if (MODE == 0) {
          v += bias[col];
          o1[(size_t)row * 1024 + col] = f2b(v);
        } else if (MODE == 1) {
          u16 h = f2b(v);
          if (o1)  o1[(size_t)row * 1024 + col] = h;
          if (o1T) o1T[(size_t)col * 1024 + row] = h;
          if (o2)  o2[(size_t)row * 4096 + o2coff + col] = h;
        } else {
          v += b2f(preb[((size_t)((row >> 3) * 32 + addct) * 8 + (row & 7)) * 1024 + col]);
          if (MODE == 2) {
            o1[(size_t)row * 1024 + col] = f2b(v);
            if (fout) fout[(size_t)row * 1024 + col] = v;
          } else {
            int t = (row >> 3) * 32 + tbase + q;
            fout[(size_t)t * 8192 + (row & 7) * 1024 + col] = v;          // h_all[t]
            float sg = 1.f / (1.f + __expf(-v));
            out0[(size_t)(t - 1) * 8192 + (row & 7) * 1024 + col] = v * v * sg;
            if (q == 4) o1[(size_t)row * 1024 + col] = f2b(v);
          }
        }
      }
}

// ---------------------------------------------------------------------------
// Flexible matvec step: out = WA*hin + (WB*adA if WB) + adB ; per-z param set.
// nr64: rows 0..63 with chunk maps; else rows 0..7 identity (pre-offset ptrs).
// ---------------------------------------------------------------------------
__global__ __launch_bounds__(256) void mv_flex(
    const float* hin0, const u16* WA0, const u16* WB0, const float* adA0,
    const float* adB0, float* ho0, u16* hb0, int acA0, int acB0, int bc0,
    const float* hin1, const u16* WA1, const u16* WB1, const float* adA1,
    const float* adB1, float* ho1, u16* hb1, int acA1, int acB1, int bc1,
    int nr64)
{
  int z = blockIdx.z;
  const float* hin = z ? hin1 : hin0;
  const u16*   WA  = z ? WA1  : WA0;
  const u16*   WB  = z ? WB1  : WB0;
  const float* adA = z ? adA1 : adA0;
  const float* adB = z ? adB1 : adB0;
  float* ho = z ? ho1 : ho0;
  u16*   hb = z ? hb1 : hb0;
  int acA = z ? acA1 : acA0, acB = z ? acB1 : acB0, bc = z ? bc1 : bc0;

  int tid = threadIdx.x, lg = tid & 15, eg = tid >> 4;
  int e = blockIdx.x * 16 + eg;
  int r0 = blockIdx.y * 8;
  float acc[8] = {0,0,0,0,0,0,0,0};
  const u16* wra = WA + (size_t)e * 1024;
  const u16* wrb = WB ? WB + (size_t)e * 1024 : nullptr;
#pragma unroll
  for (int i = 0; i < 8; ++i) {
    int d0 = lg * 8 + i * 128;
    ushort4 w0 = *(const ushort4*)(wra + d0);
    ushort4 w1 = *(const ushort4*)(wra + d0 + 4);
    float wa = b2f(w0.x), wb = b2f(w0.y), wc = b2f(w0.z), wd = b2f(w0.w);
    float we_ = b2f(w1.x), wf = b2f(w1.y), wg = b2f(w1.z), wh = b2f(w1.w);
#pragma unroll
    for (int b = 0; b < 8; ++b) {
      const float* hr = hin + (size_t)(r0 + b) * 1024 + d0;
      float4 h0v = *(const float4*)hr;
      float4 h1v = *(const float4*)(hr + 4);
      acc[b] += wa*h0v.x + wb*h0v.y + wc*h0v.z + wd*h0v.w
              + we_*h1v.x + wf*h1v.y + wg*h1v.z + wh*h1v.w;
    }
    if (wrb) {
      ushort4 b0v = *(const ushort4*)(wrb + d0);
      ushort4 b1v = *(const ushort4*)(wrb + d0 + 4);
      float ba = b2f(b0v.x), bb = b2f(b0v.y), bcc = b2f(b0v.z), bd = b2f(b0v.w);
      float be = b2f(b1v.x), bfv = b2f(b1v.y), bg = b2f(b1v.z), bh = b2f(b1v.w);
#pragma unroll
      for (int b = 0; b < 8; ++b) {
        int rr = r0 + b;
        int ar = nr64 ? (((rr >> 3) << 6) + (acA << 3) + (rr & 7)) : rr;
        const float* pr = adA + (size_t)ar * 1024 + d0;
        float4 a0v = *(const float4*)pr;
        float4 a1v = *(const float4*)(pr + 4);
        acc[b] += ba*a0v.x + bb*a0v.y + bcc*a0v.z + bd*a0v.w
                + be*a1v.x + bfv*a1v.y + bg*a1v.z + bh*a1v.w;
      }
    }
  }
#pragma unroll
  for (int m = 1; m < 16; m <<= 1)
#pragma unroll
    for (int b = 0; b < 8; ++b) acc[b] += __shfl_xor(acc[b], m);
  if (lg == 0) {
#pragma unroll
    for (int b = 0; b < 8; ++b) {
      int rr = r0 + b;
      int ai = nr64 ? (((rr >> 3) << 6) + (acB << 3) + (rr & 7)) : rr;
      float v = acc[b] + adB[(size_t)ai * 1024 + e];
      ho[(size_t)rr * 1024 + e] = v;
      if (hb) {
        int bi = nr64 ? (((rr >> 3) << 6) + (bc << 3) + (rr & 7)) : rr;
        hb[(size_t)bi * 1024 + e] = f2b(v);
      }
    }
  }
}

// ---- power iteration + misc helpers -----------------------------------------
__global__ void k_init(const float* __restrict__ u_in, const float* __restrict__ h0,
                       float* __restrict__ u_cur, float* __restrict__ v_acc,
                       float* __restrict__ u_acc, float* __restrict__ hall0,
                       float* __restrict__ bndS, u16* __restrict__ bndb)
{
  int i = blockIdx.x * 256 + threadIdx.x;
  if (i < 1024) { u_cur[i] = u_in[i]; v_acc[i] = 0.f; u_acc[i] = 0.f; }
  if (i < 8192) { float h = h0[i]; hall0[i] = h; bndS[i] = h; bndb[i] = f2b(h); }
}

__global__ void k_v(const float* __restrict__ W, const float* __restrict__ u_cur,
                    float* __restrict__ v_acc)
{
  int d = blockIdx.x * 256 + threadIdx.x;
  int e0 = blockIdx.y * 64;
  float a = 0.f;
  for (int e = e0; e < e0 + 64; ++e) a += W[(size_t)e * 1024 + d] * u_cur[e];
  atomicAdd(&v_acc[d], a);
}

__global__ void k_u(const float* __restrict__ W, const float* __restrict__ v_cur,
                    float* __restrict__ u_acc)
{
  int lg = threadIdx.x & 15, ei = threadIdx.x >> 4;
  int e = blockIdx.y * 16 + ei;
  int d0 = blockIdx.x * 512;
  float a = 0.f;
  for (int i = 0; i < 32; ++i) { int d = d0 + lg + 16 * i; a += W[(size_t)e * 1024 + d] * v_cur[d]; }
#pragma unroll
  for (int m = 1; m < 16; m <<= 1) a += __shfl_xor(a, m);
  if (lg == 0) atomicAdd(&u_acc[e], a);
}

__global__ void k_norm(const float* __restrict__ acc, float* __restrict__ outv,
                       float* __restrict__ z1)
{
  __shared__ float red[16];
  int t = threadIdx.x;
  float x = acc[t];
  float ss = x * x;
#pragma unroll
  for (int m = 1; m < 64; m <<= 1) ss += __shfl_xor(ss, m);
  if ((t & 63) == 0) red[t >> 6] = ss;
  __syncthreads();
  if (t < 64) {
    float s = (t < 16) ? red[t] : 0.f;
#pragma unroll
    for (int m = 1; m < 16; m <<= 1) s += __shfl_xor(s, m);
    if (t == 0) red[0] = s;
  }
  __syncthreads();
  float nrm = sqrtf(red[0]) + 1e-8f;
  outv[t] = x / nrm;
  z1[t] = 0.f;
}

__global__ void k_sigma(const float* __restrict__ acc, float* __restrict__ scale)
{
  __shared__ float red[16];
  int t = threadIdx.x;
  float x = acc[t];
  float ss = x * x;
#pragma unroll
  for (int m = 1; m < 64; m <<= 1) ss += __shfl_xor(ss, m);
  if ((t & 63) == 0) red[t >> 6] = ss;
  __syncthreads();
  if (t < 64) {
    float s = (t < 16) ? red[t] : 0.f;
#pragma unroll
    for (int m = 1; m < 16; m <<= 1) s += __shfl_xor(s, m);
    if (t == 0) {
      float sigma = s / (sqrtf(s) + 1e-8f);
      scale[0] = 0.95f / (sigma + 1e-8f);
    }
  }
}

// Wh_bf16, Wh^T_bf16, and Bcat slot 3 (cols 3072..4095)
__global__ void k_scale(const float* __restrict__ W, const float* __restrict__ scale,
                        u16* __restrict__ wb, u16* __restrict__ wbT,
                        u16* __restrict__ bcat)
{
  int i = blockIdx.x * 256 + threadIdx.x;
  float v = W[i] * scale[0];
  u16 h = f2b(v);
  int e = i >> 10, d = i & 1023;
  wb[i] = h;
  wbT[(size_t)d * 1024 + e] = h;
  bcat[(size_t)e * 4096 + 3072 + d] = h;
}

__global__ void k_cvt(const float* __restrict__ in, u16* __restrict__ out, int n)
{
  int i = (blockIdx.x * 256 + threadIdx.x) * 4;
  if (i >= n) return;
  float4 v = *(const float4*)(in + i);
  ushort4 o;
  o.x = f2b(v.x); o.y = f2b(v.y); o.z = f2b(v.z); o.w = f2b(v.w);
  *(ushort4*)(out + i) = o;
}

// lam0[s*8+b] = lC row s*64+b  (Lambda_1)
__global__ void k_gather(const float* __restrict__ lC, float* __restrict__ lam0)
{
  int i = blockIdx.x * 256 + threadIdx.x;   // 64 blocks
  int r = i >> 8;
  int e4 = (i & 255) * 4;
  int src = ((r >> 3) << 6) + (r & 7);
  *(float4*)(lam0 + (size_t)r * 1024 + e4) = *(const float4*)(lC + (size_t)src * 1024 + e4);
}

extern "C" void kernel_launch(void* const* d_in, const int* in_sizes, int n_in,
                              void* d_out, int out_size, void* d_ws, size_t ws_size,
                              hipStream_t stream)
{
  (void)in_sizes; (void)n_in; (void)out_size; (void)ws_size;
  const float* x  = (const float*)d_in[0];   // [2048,8,1024]
  const float* h0 = (const float*)d_in[1];   // [8,1024]
  const float* Wx = (const float*)d_in[2];   // [1024,1024]
  const float* Wh = (const float*)d_in[3];   // [1024,1024]
  const float* bv = (const float*)d_in[4];   // [1024]
  const float* uv = (const float*)d_in[5];   // [1024]

  float* out0 = (float*)d_out;               // [2048,8,1024]
  float* hall = out0 + 16777216;             // [2049,8,1024]

  // ---- ws layout (all read during phase 3 or small state) ----
  char* ws = (char*)d_ws;
  u16*   pre_b = (u16*)(ws);                  // 32 MB [16384,1024] bf16
  u16*   Bcat  = (u16*)(ws + 33554432);       // 8 MB  [1024,4096]: W4|W3|W2|W
  u16*   lb0   = (u16*)(ws + 41943040);       // 1 MB chain ping
  u16*   lb1   = (u16*)(ws + 42991616);       // 1 MB chain pong
  u16*   bnd_b = (u16*)(ws + 44040192);       // 1 MB [512,1024] chunk boundaries bf16
  float* lC    = (float*)(ws + 45088768);     // 2 MB [512,1024] fp32 chunk finals
  float* lam0  = (float*)(ws + 47185920);     // 256 KB
  float* lam1  = (float*)(ws + 47448064);     // 256 KB
  float* bndS  = (float*)(ws + 47710208);     // 256 KB superchunk boundaries fp32
  float* pc0   = (float*)(ws + 47972352);     // 256 KB
  float* pc1   = (float*)(ws + 48234496);     // 256 KB
  float* dumv  = (float*)(ws + 48496640);     // 256 KB dummy sink
  float* u_cur = (float*)(ws + 48758784);
  float* v_cur = u_cur + 1024;
  float* v_acc = u_cur + 2048;
  float* u_acc = u_cur + 3072;
  float* scale = u_cur + 4096;

  // ---- scratch inside d_out (dead before the phases that overwrite it) ----
  u16*  xb = (u16*)d_out;                     // x bf16, first 32 MB of out0
  char* HB = (char*)hall;                     // hall region scratch (dead until phase 3)
  u16* wh_b  = (u16*)(HB + 16777216);
  u16* whT_b = (u16*)(HB + 18874368);
  u16* wxb   = (u16*)(HB + 20971520);
  u16* P0    = (u16*)(HB + 23068672);
  u16* P0T   = (u16*)(HB + 25165824);
  u16* P1    = (u16*)(HB + 27262976);
  u16* P1T   = (u16*)(HB + 29360128);
  u16* W32   = (u16*)(HB + 31457280);
  u16* W64   = (u16*)(HB + 33554432);
  u16* W256  = (u16*)(HB + 35651584);
  u16* W512  = (u16*)(HB + 37748736);

  const u16* NU = nullptr; u16* NUo = nullptr; float* NUf = nullptr;

  k_init<<<32, 256, 0, stream>>>(uv, h0, u_cur, v_acc, u_acc, hall, bndS, bnd_b);

  for (int it = 0; it < 3; ++it) {
    k_v<<<dim3(4, 16), 256, 0, stream>>>(Wh, u_cur, v_acc);
    k_norm<<<1, 1024, 0, stream>>>(v_acc, v_cur, u_acc);
    k_u<<<dim3(2, 64), 256, 0, stream>>>(Wh, v_cur, u_acc);
    if (it < 2) k_norm<<<1, 1024, 0, stream>>>(u_acc, u_cur, v_acc);
    else        k_sigma<<<1, 1024, 0, stream>>>(u_acc, scale);
  }
  k_scale<<<4096, 256, 0, stream>>>(Wh, scale, wh_b, whT_b, Bcat);

  k_cvt<<<16384, 256, 0, stream>>>(x, xb, 16777216);
  k_cvt<<<1024, 256, 0, stream>>>(Wx, wxb, 1048576);

  // pre = x @ Wx^T + b
  gK<0><<<dim3(16, 256), 256, 0, stream>>>(xb, NU, 0, 0u, 1, 0, wxb, 1024,
                                           bv, 0, pre_b, NUo, NUo, 0, NUf, NUf, 0);

  // ---- Wh powers (A*B^T form, carrying transposes) ----
  // S1: W2
  gK<1><<<dim3(16, 16), 256, 0, stream>>>(wh_b, NU, 0, 0u, 1, 0, whT_b, 1024,
                                          nullptr, 0, P0, P0T, Bcat, 2048, NUf, NUf, 0);
  // S2a: W3 -> Bcat slot1 only
  gK<1><<<dim3(16, 16), 256, 0, stream>>>(P0, NU, 0, 0u, 1, 0, whT_b, 1024,
                                          nullptr, 0, NUo, NUo, Bcat, 1024, NUf, NUf, 0);
  // S2b: W4
  gK<1><<<dim3(16, 16), 256, 0, stream>>>(P0, NU, 0, 0u, 1, 0, P0T, 1024,
                                          nullptr, 0, P1, P1T, Bcat, 0, NUf, NUf, 0);
  // S3: W8 = W4*W4
  gK<1><<<dim3(16, 16), 256, 0, stream>>>(P1, NU, 0, 0u, 1, 0, P1T, 1024,
                                          nullptr, 0, P0, P0T, NUo, 0, NUf, NUf, 0);
  // S4: W16
  gK<1><<<dim3(16, 16), 256, 0, stream>>>(P0, NU, 0, 0u, 1, 0, P0T, 1024,
                                          nullptr, 0, P1, P1T, NUo, 0, NUf, NUf, 0);
  // S5: W32 (T in P0T)
  gK<1><<<dim3(16, 16), 256, 0, stream>>>(P1, NU, 0, 0u, 1, 0, P1T, 1024,
                                          nullptr, 0, W32, P0T, NUo, 0, NUf, NUf, 0);
  // S6: W64 (T in P1T)
  gK<1><<<dim3(16, 16), 256, 0, stream>>>(W32, NU, 0, 0u, 1, 0, P0T, 1024,
                                          nullptr, 0, W64, P1T, NUo, 0, NUf, NUf, 0);
  // S7: W128 -> P0/P0T
  gK<1><<<dim3(16, 16), 256, 0, stream>>>(W64, NU, 0, 0u, 1, 0, P1T, 1024,
                                          nullptr, 0, P0, P0T, NUo, 0, NUf, NUf, 0);
  // S8: W256 (T in P1T)
  gK<1><<<dim3(16, 16), 256, 0, stream>>>(P0, NU, 0, 0u, 1, 0, P0T, 1024,
                                          nullptr, 0, W256, P1T, NUo, 0, NUf, NUf, 0);
  // S9: W512
  gK<1><<<dim3(16, 16), 256, 0, stream>>>(W256, NU, 0, 0u, 1, 0, P1T, 1024,
                                          nullptr, 0, W512, NUo, NUo, 0, NUf, NUf, 0);

  // ---- phase 1: 8 quad-steps; l_{c+4} = W4 l_c + W3 p_c + W2 p_{c+1} + W p_{c+2} + p_{c+3}
  for (int k = 1; k <= 8; ++k) {
    int c = 4 * (k - 1);
    u16* out = (k & 1) ? lb0 : lb1;
    const u16* in = ((k - 1) & 1) ? lb0 : lb1;   // out of k-1
    if (k == 1)
      gK<2><<<dim3(16, 8), 256, 0, stream>>>(NU, pre_b, 0, 0x7u, 3, 1024, Bcat, 4096,
                                             nullptr, 3, out, NUo, NUo, 0, NUf, NUf, 0);
    else
      gK<2><<<dim3(16, 8), 256, 0, stream>>>(in, pre_b, c - 1, 0xEu, 4, 0, Bcat, 4096,
                                             nullptr, c + 3, out, NUo, NUo, 0,
                                             (k == 8) ? lC : NUf, NUf, 0);
  }

  // ---- gather Lambda_1 ----
  k_gather<<<64, 256, 0, stream>>>(lC, lam0);

  // ---- phase 2a: Lambda 1->3->5->7->8 (3x mv2 + 1x mv1) ----
  mv_flex<<<dim3(64, 8, 1), 256, 0, stream>>>(
      lam0, W64, W32, lC, lC, lam1, NUo, 1, 2, 0,
      NUf, NU, NU, NUf, NUf, NUf, NUo, 0, 0, 0, 1);
  mv_flex<<<dim3(64, 8, 1), 256, 0, stream>>>(
      lam1, W64, W32, lC, lC, lam0, NUo, 3, 4, 0,
      NUf, NU, NU, NUf, NUf, NUf, NUo, 0, 0, 0, 1);
  mv_flex<<<dim3(64, 8, 1), 256, 0, stream>>>(
      lam0, W64, W32, lC, lC, lam1, NUo, 5, 6, 0,
      NUf, NU, NU, NUf, NUf, NUf, NUo, 0, 0, 0, 1);
  mv_flex<<<dim3(64, 8, 1), 256, 0, stream>>>(
      lam1, W32, NU, NUf, lC, lam0, NUo, 0, 7, 0,
      NUf, NU, NU, NUf, NUf, NUf, NUo, 0, 0, 0, 1);
  // Lambda_8 in lam0 (rows s*8+b)

  // ---- phase 2b: superchunk chain b0->(b1,b2)->(b3,b4)->(b5,b6)->b7 ----
  for (int s = 0; s < 3; ++s) {
    float* bs = bndS + (size_t)2 * s * 8192;
    mv_flex<<<dim3(64, 1, 2), 256, 0, stream>>>(
        bs, W256, NU, NUf, lam0 + (size_t)2 * s * 8192,
        bs + 8192, bnd_b + (size_t)(2 * s + 1) * 65536, 0, 0, 0,
        bs, W512, W256, lam0 + (size_t)2 * s * 8192, lam0 + (size_t)(2 * s + 1) * 8192,
        bs + 16384, bnd_b + (size_t)(2 * s + 2) * 65536, 0, 0, 0, 0);
  }
  mv_flex<<<dim3(64, 1, 1), 256, 0, stream>>>(
      bndS + (size_t)6 * 8192, W256, NU, NUf, lam0 + (size_t)6 * 8192,
      bndS + (size_t)7 * 8192, bnd_b + (size_t)7 * 65536, 0, 0, 0,
      NUf, NU, NU, NUf, NUf, NUf, NUo, 0, 0, 0, 0);

  // ---- phase 2c: intra-super boundaries c=1..7 (pairs) ----
  mv_flex<<<dim3(64, 8, 2), 256, 0, stream>>>(
      bndS, W32, NU, NUf, lC, dumv, bnd_b, 0, 0, 1,
      bndS, W64, W32, lC, lC, pc0, bnd_b, 0, 1, 2, 1);
  mv_flex<<<dim3(64, 8, 2), 256, 0, stream>>>(
      pc0, W32, NU, NUf, lC, dumv, bnd_b, 0, 2, 3,
      pc0, W64, W32, lC, lC, pc1, bnd_b, 2, 3, 4, 1);
  mv_flex<<<dim3(64, 8, 2), 256, 0, stream>>>(
      pc1, W32, NU, NUf, lC, dumv, bnd_b, 0, 4, 5,
      pc1, W64, W32, lC, lC, pc0, bnd_b, 4, 5, 6, 1);
  mv_flex<<<dim3(64, 8, 1), 256, 0, stream>>>(
      pc0, W32, NU, NUf, lC, dumv, bnd_b, 0, 6, 7,
      NUf, NU, NU, NUf, NUf, NUf, NUo, 0, 0, 0, 1);

  // ---- phase 3: 8 quad-steps, z=q-1 in {0..3}; fused h_all + h^2*silu ----
  for (int k = 0; k <= 7; ++k) {
    int c = 4 * k;
    const u16* in = (k == 0) ? bnd_b : ((k & 1) ? lb0 : lb1);
    u16* out = (k & 1) ? lb1 : lb0;
    gK<3><<<dim3(16, 8, 4), 256, 0, stream>>>(in, pre_b, c - 1, 0xEu, 0, 0, Bcat, 4096,
                                              nullptr, 0, out, NUo, NUo, 0,
                                              hall, out0, c);
  }
}